// Round 16
// baseline (23.410 us; speedup 1.0000x reference)
//
#include <hip/hip_runtime.h>

#define B_   16
#define T_   10
#define D_   256
#define MI_  32
#define MO_  16
#define RES_ 200
#define TWO_PI 6.28318530717958647692f

#define HSLICE 32
#define NHS    (D_ / HSLICE)              // 8
#define VPAD   68
#define BT_STRIDE (2 * MO_ * D_)          // 8192 floats: [o][h] -> (C,S) pairs

using f32x4 = __attribute__((ext_vector_type(4))) float;
using v2f   = __attribute__((ext_vector_type(2))) float;

// ---------- Kernel A: contraction -> ws[bt][o][h] = (C,S) interleaved ------
// grid 1280; XCD-aligned: blk%8 = bt%8. ROUND-11/15 EXACT (~7.3us incl launch).
__global__ __launch_bounds__(256) void spectral_cs(
    const float* __restrict__ v,
    const float* __restrict__ w_real,
    const float* __restrict__ w_imag,
    float* __restrict__ ws)
{
    const int a    = blockIdx.x;
    const int r    = a & 7;
    const int rest = a >> 3;           // 0..159
    const int hs   = rest & 7;
    const int q    = rest >> 3;        // 0..19
    const int bt   = 8 * q + r;
    const int t    = bt % T_;

    __shared__ float s_v[HSLICE * VPAD];     // 8.5 KB

    {   // cooperative v-slice stage (v read exactly once per element)
        const float4* gv = reinterpret_cast<const float4*>(
            v + ((size_t)bt * D_ + hs * HSLICE) * (2 * MI_));
        #pragma unroll
        for (int j = 0; j < 2; ++j) {
            const int f = threadIdx.x + 256 * j;
            const int h = f >> 4;
            const int m = (f & 15) * 4;
            *reinterpret_cast<float4*>(&s_v[h * VPAD + m]) = gv[f];
        }
    }
    __syncthreads();

    const int og  = threadIdx.x >> 5;
    const int h_l = threadIdx.x & 31;
    const int o0  = og * 2;
    const int h_g = hs * HSLICE + h_l;

    float rr[MI_], ii[MI_];
    #pragma unroll
    for (int j = 0; j < 8; ++j) {
        float4 q4 = *reinterpret_cast<const float4*>(&s_v[h_l * VPAD + 4 * j]);
        rr[4*j+0]=q4.x; rr[4*j+1]=q4.y; rr[4*j+2]=q4.z; rr[4*j+3]=q4.w;
    }
    #pragma unroll
    for (int j = 0; j < 8; ++j) {
        float4 q4 = *reinterpret_cast<const float4*>(&s_v[h_l * VPAD + 32 + 4 * j]);
        ii[4*j+0]=q4.x; ii[4*j+1]=q4.y; ii[4*j+2]=q4.z; ii[4*j+3]=q4.w;
    }

    const float* wrt = w_real + ((size_t)t * MO_ + o0) * MI_;
    const float* wit = w_imag + ((size_t)t * MO_ + o0) * MI_;

    float* wsb = ws + (size_t)bt * BT_STRIDE;
    #pragma unroll
    for (int ol = 0; ol < 2; ++ol) {
        const float4* wa = reinterpret_cast<const float4*>(wrt + ol * MI_);
        const float4* wb = reinterpret_cast<const float4*>(wit + ol * MI_);
        float c = 0.f, s = 0.f;
        #pragma unroll
        for (int mq = 0; mq < 8; ++mq) {
            float4 a4 = wa[mq];
            float4 b4 = wb[mq];
            c = fmaf(rr[4*mq+0], a4.x, c); c = fmaf(-ii[4*mq+0], b4.x, c);
            s = fmaf(rr[4*mq+0], b4.x, s); s = fmaf( ii[4*mq+0], a4.x, s);
            c = fmaf(rr[4*mq+1], a4.y, c); c = fmaf(-ii[4*mq+1], b4.y, c);
            s = fmaf(rr[4*mq+1], b4.y, s); s = fmaf( ii[4*mq+1], a4.y, s);
            c = fmaf(rr[4*mq+2], a4.z, c); c = fmaf(-ii[4*mq+2], b4.z, c);
            s = fmaf(rr[4*mq+2], b4.z, s); s = fmaf( ii[4*mq+2], a4.z, s);
            c = fmaf(rr[4*mq+3], a4.w, c); c = fmaf(-ii[4*mq+3], b4.w, c);
            s = fmaf(rr[4*mq+3], b4.w, s); s = fmaf( ii[4*mq+3], a4.w, s);
        }
        const int o = o0 + ol;
        v2f p; p.x = c; p.y = s;
        // interleaved pair store: 32 lanes x 8B = 256B contiguous run
        *reinterpret_cast<v2f*>(&wsb[2 * (o * D_ + h_g)]) = p;
    }
}

// ---------- Kernel B v4: v3 with REGULAR stores (NT removed) ---------------
// Single-variable test vs round 15: out stores go through L2 (per-XCD slice
// ~4MB fits L2; writeback streams sequentially) instead of NT->HBM scattered.
__global__ __launch_bounds__(256) void spectral_ift(
    const float* __restrict__ ws,
    float* __restrict__ out)
{
    const int b    = blockIdx.x;
    const int r    = b & 7;
    const int rest = b >> 3;           // 0..79
    const int qb   = rest & 3;
    const int q    = rest >> 2;        // 0..19
    const int bt   = 8 * q + r;
    const int wave = threadIdx.x >> 6;
    const int lane = threadIdx.x & 63;
    const int g    = qb * 4 + wave;    // 0..15
    const int h0   = lane * 4;

    // per-lane C,S registers straight from global (16 overlapped b128 loads)
    const float* wsb = ws + (size_t)bt * BT_STRIDE;
    v2f CS0[MO_], CS1[MO_], CS2[MO_], CS3[MO_];
    #pragma unroll
    for (int o = 0; o < MO_; ++o) {
        float4 q0 = *reinterpret_cast<const float4*>(&wsb[2 * (o * D_ + h0)]);
        float4 q1 = *reinterpret_cast<const float4*>(&wsb[2 * (o * D_ + h0) + 4]);
        CS0[o].x = q0.x; CS0[o].y = q0.y;
        CS1[o].x = q0.z; CS1[o].y = q0.w;
        CS2[o].x = q1.x; CS2[o].y = q1.y;
        CS3[o].x = q1.z; CS3[o].y = q1.w;
    }

    // hoisted slot trig (independent of the loads -> fills the load shadow)
    float cph[7], sph[7];
    #pragma unroll
    for (int k = 0; k < 7; ++k) {
        const int s = g + 16 * k;
        const float phi = (float)s * (TWO_PI / (float)RES_);
        __sincosf(phi, &sph[k], &cph[k]);
    }

    float* ob = out + (size_t)bt * RES_ * D_;

    #pragma unroll
    for (int k = 0; k < 7; ++k) {
        const int s = g + 16 * k;        // wave-uniform slot
        if (s <= 100) {
            const float c1 = cph[k];
            const float s1 = sph[k];

            v2f ab0 = {0.f, 0.f}, ab1 = {0.f, 0.f};
            v2f ab2 = {0.f, 0.f}, ab3 = {0.f, 0.f};
            v2f cs;  cs.x = 1.f; cs.y = 0.f;      // (cos(o*phi), sin(o*phi))
            #pragma unroll
            for (int o = 0; o < MO_; ++o) {
                ab0 = __builtin_elementwise_fma(CS0[o], cs, ab0);
                ab1 = __builtin_elementwise_fma(CS1[o], cs, ab1);
                ab2 = __builtin_elementwise_fma(CS2[o], cs, ab2);
                ab3 = __builtin_elementwise_fma(CS3[o], cs, ab3);
                const float nc = fmaf(cs.x, c1, -(cs.y * s1));
                const float ns = fmaf(cs.y, c1,  (cs.x * s1));
                cs.x = nc; cs.y = ns;
            }

            f32x4 lo, hi;
            lo.x = ab0.x - ab0.y; hi.x = ab0.x + ab0.y;
            lo.y = ab1.x - ab1.y; hi.y = ab1.x + ab1.y;
            lo.z = ab2.x - ab2.y; hi.z = ab2.x + ab2.y;
            lo.w = ab3.x - ab3.y; hi.w = ab3.x + ab3.y;
            // full-row wave store: 64 lanes x 16B = 1KB contiguous, via L2
            *reinterpret_cast<f32x4*>(&ob[(size_t)s * D_ + h0]) = lo;
            if (s != 0) {
                const int mr = RES_ - s;
                *reinterpret_cast<f32x4*>(&ob[(size_t)mr * D_ + h0]) = hi;
            }
        }
    }
}

extern "C" void kernel_launch(void* const* d_in, const int* in_sizes, int n_in,
                              void* d_out, int out_size, void* d_ws, size_t ws_size,
                              hipStream_t stream) {
    const float* v  = (const float*)d_in[0];
    const float* wr = (const float*)d_in[1];
    const float* wi = (const float*)d_in[2];
    float* out = (float*)d_out;
    float* ws  = (float*)d_ws;

    spectral_cs <<<B_ * T_ * NHS, 256, 0, stream>>>(v, wr, wi, ws);
    spectral_ift<<<B_ * T_ * 4,   256, 0, stream>>>(ws, out);
}

// Round 17
// 21.244 us; speedup vs baseline: 1.1020x; 1.1020x over previous
//
#include <hip/hip_runtime.h>

#define B_   16
#define T_   10
#define D_   256
#define MI_  32
#define MO_  16
#define RES_ 200
#define TWO_PI 6.28318530717958647692f

#define HSLICE 32
#define NHS    (D_ / HSLICE)              // 8
#define VPAD   68
#define BT_STRIDE (2 * MO_ * D_)          // 8192 floats: [o][h] -> (C,S) pairs

using f32x4 = __attribute__((ext_vector_type(4))) float;
using v2f   = __attribute__((ext_vector_type(2))) float;

// ---------- Kernel A: contraction -> ws[bt][o][h] = (C,S) interleaved ------
// grid 1280; XCD-aligned: blk%8 = bt%8. ROUND-11/15 EXACT (~7.3us incl launch).
__global__ __launch_bounds__(256) void spectral_cs(
    const float* __restrict__ v,
    const float* __restrict__ w_real,
    const float* __restrict__ w_imag,
    float* __restrict__ ws)
{
    const int a    = blockIdx.x;
    const int r    = a & 7;
    const int rest = a >> 3;           // 0..159
    const int hs   = rest & 7;
    const int q    = rest >> 3;        // 0..19
    const int bt   = 8 * q + r;
    const int t    = bt % T_;

    __shared__ float s_v[HSLICE * VPAD];     // 8.5 KB

    {   // cooperative v-slice stage (v read exactly once per element)
        const float4* gv = reinterpret_cast<const float4*>(
            v + ((size_t)bt * D_ + hs * HSLICE) * (2 * MI_));
        #pragma unroll
        for (int j = 0; j < 2; ++j) {
            const int f = threadIdx.x + 256 * j;
            const int h = f >> 4;
            const int m = (f & 15) * 4;
            *reinterpret_cast<float4*>(&s_v[h * VPAD + m]) = gv[f];
        }
    }
    __syncthreads();

    const int og  = threadIdx.x >> 5;
    const int h_l = threadIdx.x & 31;
    const int o0  = og * 2;
    const int h_g = hs * HSLICE + h_l;

    float rr[MI_], ii[MI_];
    #pragma unroll
    for (int j = 0; j < 8; ++j) {
        float4 q4 = *reinterpret_cast<const float4*>(&s_v[h_l * VPAD + 4 * j]);
        rr[4*j+0]=q4.x; rr[4*j+1]=q4.y; rr[4*j+2]=q4.z; rr[4*j+3]=q4.w;
    }
    #pragma unroll
    for (int j = 0; j < 8; ++j) {
        float4 q4 = *reinterpret_cast<const float4*>(&s_v[h_l * VPAD + 32 + 4 * j]);
        ii[4*j+0]=q4.x; ii[4*j+1]=q4.y; ii[4*j+2]=q4.z; ii[4*j+3]=q4.w;
    }

    const float* wrt = w_real + ((size_t)t * MO_ + o0) * MI_;
    const float* wit = w_imag + ((size_t)t * MO_ + o0) * MI_;

    float* wsb = ws + (size_t)bt * BT_STRIDE;
    #pragma unroll
    for (int ol = 0; ol < 2; ++ol) {
        const float4* wa = reinterpret_cast<const float4*>(wrt + ol * MI_);
        const float4* wb = reinterpret_cast<const float4*>(wit + ol * MI_);
        float c = 0.f, s = 0.f;
        #pragma unroll
        for (int mq = 0; mq < 8; ++mq) {
            float4 a4 = wa[mq];
            float4 b4 = wb[mq];
            c = fmaf(rr[4*mq+0], a4.x, c); c = fmaf(-ii[4*mq+0], b4.x, c);
            s = fmaf(rr[4*mq+0], b4.x, s); s = fmaf( ii[4*mq+0], a4.x, s);
            c = fmaf(rr[4*mq+1], a4.y, c); c = fmaf(-ii[4*mq+1], b4.y, c);
            s = fmaf(rr[4*mq+1], b4.y, s); s = fmaf( ii[4*mq+1], a4.y, s);
            c = fmaf(rr[4*mq+2], a4.z, c); c = fmaf(-ii[4*mq+2], b4.z, c);
            s = fmaf(rr[4*mq+2], b4.z, s); s = fmaf( ii[4*mq+2], a4.z, s);
            c = fmaf(rr[4*mq+3], a4.w, c); c = fmaf(-ii[4*mq+3], b4.w, c);
            s = fmaf(rr[4*mq+3], b4.w, s); s = fmaf( ii[4*mq+3], a4.w, s);
        }
        const int o = o0 + ol;
        v2f p; p.x = c; p.y = s;
        // interleaved pair store: 32 lanes x 8B = 256B contiguous run
        *reinterpret_cast<v2f*>(&wsb[2 * (o * D_ + h_g)]) = p;
    }
}

// ---------- Kernel B: ROUND-15 EXACT (champion) + skip s=0 dup store -------
// grid 640; XCD-aligned: blk%8 = bt%8. block 256 = 4 independent waves
// (no __syncthreads). wave = full output row; lane owns h = 4*lane..4*lane+3.
// CS regs via 16 overlapped global b128 loads (L2-local); hoisted sincos;
// rotation-recurrence; NT 1KB contiguous wave stores (proven > regular).
__global__ __launch_bounds__(256) void spectral_ift(
    const float* __restrict__ ws,
    float* __restrict__ out)
{
    const int b    = blockIdx.x;
    const int r    = b & 7;
    const int rest = b >> 3;           // 0..79
    const int qb   = rest & 3;
    const int q    = rest >> 2;        // 0..19
    const int bt   = 8 * q + r;
    const int wave = threadIdx.x >> 6;
    const int lane = threadIdx.x & 63;
    const int g    = qb * 4 + wave;    // 0..15
    const int h0   = lane * 4;

    // per-lane C,S registers straight from global (16 overlapped b128 loads)
    const float* wsb = ws + (size_t)bt * BT_STRIDE;
    v2f CS0[MO_], CS1[MO_], CS2[MO_], CS3[MO_];
    #pragma unroll
    for (int o = 0; o < MO_; ++o) {
        float4 q0 = *reinterpret_cast<const float4*>(&wsb[2 * (o * D_ + h0)]);
        float4 q1 = *reinterpret_cast<const float4*>(&wsb[2 * (o * D_ + h0) + 4]);
        CS0[o].x = q0.x; CS0[o].y = q0.y;
        CS1[o].x = q0.z; CS1[o].y = q0.w;
        CS2[o].x = q1.x; CS2[o].y = q1.y;
        CS3[o].x = q1.z; CS3[o].y = q1.w;
    }

    // hoisted slot trig (independent of the loads -> fills the load shadow)
    float cph[7], sph[7];
    #pragma unroll
    for (int k = 0; k < 7; ++k) {
        const int s = g + 16 * k;
        const float phi = (float)s * (TWO_PI / (float)RES_);
        __sincosf(phi, &sph[k], &cph[k]);
    }

    float* ob = out + (size_t)bt * RES_ * D_;

    #pragma unroll
    for (int k = 0; k < 7; ++k) {
        const int s = g + 16 * k;        // wave-uniform slot
        if (s <= 100) {
            const float c1 = cph[k];
            const float s1 = sph[k];

            v2f ab0 = {0.f, 0.f}, ab1 = {0.f, 0.f};
            v2f ab2 = {0.f, 0.f}, ab3 = {0.f, 0.f};
            v2f cs;  cs.x = 1.f; cs.y = 0.f;      // (cos(o*phi), sin(o*phi))
            #pragma unroll
            for (int o = 0; o < MO_; ++o) {
                ab0 = __builtin_elementwise_fma(CS0[o], cs, ab0);
                ab1 = __builtin_elementwise_fma(CS1[o], cs, ab1);
                ab2 = __builtin_elementwise_fma(CS2[o], cs, ab2);
                ab3 = __builtin_elementwise_fma(CS3[o], cs, ab3);
                const float nc = fmaf(cs.x, c1, -(cs.y * s1));
                const float ns = fmaf(cs.y, c1,  (cs.x * s1));
                cs.x = nc; cs.y = ns;
            }

            f32x4 lo, hi;
            lo.x = ab0.x - ab0.y; hi.x = ab0.x + ab0.y;
            lo.y = ab1.x - ab1.y; hi.y = ab1.x + ab1.y;
            lo.z = ab2.x - ab2.y; hi.z = ab2.x + ab2.y;
            lo.w = ab3.x - ab3.y; hi.w = ab3.x + ab3.y;
            // full-row wave store: 64 lanes x 16B = 1KB contiguous (NT)
            __builtin_nontemporal_store(
                lo, reinterpret_cast<f32x4*>(&ob[(size_t)s * D_ + h0]));
            if (s != 0) {
                const int mr = RES_ - s;
                __builtin_nontemporal_store(
                    hi, reinterpret_cast<f32x4*>(&ob[(size_t)mr * D_ + h0]));
            }
        }
    }
}

extern "C" void kernel_launch(void* const* d_in, const int* in_sizes, int n_in,
                              void* d_out, int out_size, void* d_ws, size_t ws_size,
                              hipStream_t stream) {
    const float* v  = (const float*)d_in[0];
    const float* wr = (const float*)d_in[1];
    const float* wi = (const float*)d_in[2];
    float* out = (float*)d_out;
    float* ws  = (float*)d_ws;

    spectral_cs <<<B_ * T_ * NHS, 256, 0, stream>>>(v, wr, wi, ws);
    spectral_ift<<<B_ * T_ * 4,   256, 0, stream>>>(ws, out);
}